// Round 13
// baseline (1287.873 us; speedup 1.0000x reference)
//
#include <hip/hip_runtime.h>
#include <hip/hip_bf16.h>
#include <hip/hip_cooperative_groups.h>

namespace cg = cooperative_groups;

#define NN 50000
#define EE 600000
#define HH 128
#define CC 40
#define NEG 0.1f
#define CAP 40        // padded-CSR capacity; P(deg>40) ~ 1e-10
#define NTILE (NN / 16)

typedef __attribute__((ext_vector_type(8))) short bf16x8;
typedef __attribute__((ext_vector_type(4))) float f32x4;

__device__ __forceinline__ unsigned short f2bf(float f) {
    unsigned u = __float_as_uint(f);
    unsigned r = u + 0x7fffu + ((u >> 16) & 1u);
    return (unsigned short)(r >> 16);
}
__device__ __forceinline__ float bfhi(unsigned v) { return __uint_as_float(v & 0xFFFF0000u); }
__device__ __forceinline__ float bflo(unsigned v) { return __uint_as_float(v << 16); }

template <int DOUT, int DOUTP>
__device__ __forceinline__ void swz_one(const float* __restrict__ W,
                                        unsigned short* __restrict__ dstf, int idx) {
    int k = idx / DOUTP, n = idx % DOUTP;
    unsigned short val = (n < DOUT) ? f2bf(W[k * DOUT + n]) : (unsigned short)0;
    int kt = k >> 5, kin = k & 31, nt = n >> 4, nin = n & 15;
    int lane = ((kin >> 3) << 4) | nin;
    int j = kin & 7;
    int NT = DOUTP >> 4;
    dstf[(((kt * NT + nt) * 64) + lane) * 8 + j] = val;
}

// ---------------- layer tile: 2-phase gather + double GEMM + lrelu ----------------
// 512 thr = 8 waves = 16 nodes (2/wave). MODE 1: fused t = lrelu_tile @ dec_Wl.
template <int MODE>
__device__ void layer_tile(int tile, const unsigned short* __restrict__ hin,
                           const int* __restrict__ counts, const int* __restrict__ csr,
                           const unsigned short* __restrict__ B1f,
                           const unsigned short* __restrict__ B2f,
                           const float* __restrict__ bias, unsigned short* __restrict__ out,
                           const unsigned short* __restrict__ Tf,
                           unsigned short* __restrict__ tOut) {
    __shared__ unsigned lds[16][72];           // MODE1 reuses as [16][132] shorts
    __syncthreads();                           // protect LDS across tile iterations
    int wid = threadIdx.x >> 6;
    int lane = threadIdx.x & 63;
    int m0 = tile * 16;
    int g = lane & 7;
    int s = lane >> 3;
    const uint4* hw4 = (const uint4*)hin;

    int beg[2], cnt[2];
    float sc[2];
    int maxd = 0;
#pragma unroll
    for (int n = 0; n < 2; ++n) {
        int node = m0 + wid * 2 + n;
        int c = counts[node];
        c = c < CAP ? c : CAP;
        beg[n] = node * CAP;
        cnt[n] = c;
        sc[n] = 1.0f / (float)(c > 0 ? c : 1);
        maxd = maxd > c ? maxd : c;
    }
    int rounds = (maxd + 7) >> 3;

    for (int ph = 0; ph < 2; ++ph) {
        float acc[2][8];
#pragma unroll
        for (int n = 0; n < 2; ++n)
#pragma unroll
            for (int d = 0; d < 8; ++d) acc[n][d] = 0.f;

        uint4 v[2]; int ok[2];
        auto issue = [&](int r, uint4* vv, int* okk) {
#pragma unroll
            for (int n = 0; n < 2; ++n) {
                int idx = r * 8 + s;
                int o = idx < cnt[n];
                int row = csr[beg[n] + (o ? idx : 0)];
                vv[n] = hw4[(size_t)row * 16 + ph * 8 + g];
                okk[n] = o;
            }
        };
        if (rounds > 0) {
            issue(0, v, ok);
            for (int r = 0; r < rounds; ++r) {
                uint4 vn[2]; int okn[2];
                bool more = (r + 1 < rounds);
                if (more) issue(r + 1, vn, okn);
#pragma unroll
                for (int n = 0; n < 2; ++n) {
                    if (ok[n]) {
                        acc[n][0] += bflo(v[n].x); acc[n][1] += bfhi(v[n].x);
                        acc[n][2] += bflo(v[n].y); acc[n][3] += bfhi(v[n].y);
                        acc[n][4] += bflo(v[n].z); acc[n][5] += bfhi(v[n].z);
                        acc[n][6] += bflo(v[n].w); acc[n][7] += bfhi(v[n].w);
                    }
                }
                if (more) {
#pragma unroll
                    for (int n = 0; n < 2; ++n) { v[n] = vn[n]; ok[n] = okn[n]; }
                }
            }
        }
#pragma unroll
        for (int n = 0; n < 2; ++n) {
#pragma unroll
            for (int d = 0; d < 8; ++d) {
                float t = acc[n][d];
                t += __shfl_xor(t, 8, 64);
                t += __shfl_xor(t, 16, 64);
                t += __shfl_xor(t, 32, 64);
                acc[n][d] = t;
            }
            if (s == 0) {
                uint4 w4;
                w4.x = ((unsigned)f2bf(acc[n][1] * sc[n]) << 16) | f2bf(acc[n][0] * sc[n]);
                w4.y = ((unsigned)f2bf(acc[n][3] * sc[n]) << 16) | f2bf(acc[n][2] * sc[n]);
                w4.z = ((unsigned)f2bf(acc[n][5] * sc[n]) << 16) | f2bf(acc[n][4] * sc[n]);
                w4.w = ((unsigned)f2bf(acc[n][7] * sc[n]) << 16) | f2bf(acc[n][6] * sc[n]);
                *(uint4*)&lds[wid * 2 + n][ph * 32 + g * 4] = w4;
            }
        }
    }
    __syncthreads();

    int nin = lane & 15;
    int kq = lane >> 4;
    const unsigned* arow = &lds[nin][0];

    f32x4 acc1 = (f32x4){0.f, 0.f, 0.f, 0.f};
#pragma unroll
    for (int kt = 0; kt < 4; ++kt) {
        bf16x8 a1 = *(const bf16x8*)(arow + kt * 16 + kq * 4);
        bf16x8 a2 = *(const bf16x8*)(hin + (size_t)(m0 + nin) * HH + kt * 32 + kq * 8);
        bf16x8 b1 = *(const bf16x8*)(B1f + (((kt * 8 + wid) * 64) + lane) * 8);
        acc1 = __builtin_amdgcn_mfma_f32_16x16x32_bf16(a1, b1, acc1, 0, 0, 0);
        bf16x8 b2 = *(const bf16x8*)(B2f + (((kt * 8 + wid) * 64) + lane) * 8);
        acc1 = __builtin_amdgcn_mfma_f32_16x16x32_bf16(a2, b2, acc1, 0, 0, 0);
    }

    int col = wid * 16 + nin;
    float bv = bias[col];
    unsigned short hv[4];
#pragma unroll
    for (int r = 0; r < 4; ++r) {
        int m = m0 + kq * 4 + r;
        float v = acc1[r] + bv;
        v = fmaxf(v, NEG * v);
        hv[r] = f2bf(v);
        out[(size_t)m * HH + col] = hv[r];
    }

    if (MODE == 1) {
        __syncthreads();
        unsigned short* lsh = (unsigned short*)&lds[0][0];   // [16][132] shorts
#pragma unroll
        for (int r = 0; r < 4; ++r) lsh[(kq * 4 + r) * 132 + col] = hv[r];
        __syncthreads();
        if (wid < 3) {
            f32x4 at = (f32x4){0.f, 0.f, 0.f, 0.f};
#pragma unroll
            for (int kt = 0; kt < 4; ++kt) {
                bf16x8 a = *(const bf16x8*)&lsh[nin * 132 + kt * 32 + kq * 8];
                bf16x8 b = *(const bf16x8*)(Tf + (((kt * 3 + wid) * 64) + lane) * 8);
                at = __builtin_amdgcn_mfma_f32_16x16x32_bf16(a, b, at, 0, 0, 0);
            }
#pragma unroll
            for (int r = 0; r < 4; ++r) {
                int m = m0 + kq * 4 + r;
                tOut[(size_t)m * 48 + wid * 16 + nin] = f2bf(at[r]);
            }
        }
    }
}

// ---------------- dec tile: gather t (96B rows) + h1@Wr + log_softmax ----------------
__device__ void dec_tile(int tile, const unsigned short* __restrict__ tbuf,
                         const unsigned short* __restrict__ h1,
                         const int* __restrict__ counts, const int* __restrict__ csr,
                         const unsigned short* __restrict__ B2f,
                         const float* __restrict__ bias, float* __restrict__ out) {
    __shared__ float aggT[16][52];
    __syncthreads();                           // protect LDS across tile iterations
    int wid = threadIdx.x >> 6;
    int lane = threadIdx.x & 63;
    int m0 = tile * 16;
    int g = lane & 7;
    int g6 = g < 6 ? g : g - 6;
    int s = lane >> 3;
    const uint4* t4 = (const uint4*)tbuf;

    int beg[2], cnt[2];
    float sc[2];
    int maxd = 0;
#pragma unroll
    for (int n = 0; n < 2; ++n) {
        int node = m0 + wid * 2 + n;
        int c = counts[node];
        c = c < CAP ? c : CAP;
        beg[n] = node * CAP;
        cnt[n] = c;
        sc[n] = 1.0f / (float)(c > 0 ? c : 1);
        maxd = maxd > c ? maxd : c;
    }
    int rounds = (maxd + 7) >> 3;

    float acc[2][8];
#pragma unroll
    for (int n = 0; n < 2; ++n)
#pragma unroll
        for (int d = 0; d < 8; ++d) acc[n][d] = 0.f;

    uint4 v[2]; int ok[2];
    auto issue = [&](int r, uint4* vv, int* okk) {
#pragma unroll
        for (int n = 0; n < 2; ++n) {
            int idx = r * 8 + s;
            int o = idx < cnt[n];
            int row = csr[beg[n] + (o ? idx : 0)];
            vv[n] = t4[(size_t)row * 6 + g6];
            okk[n] = o;
        }
    };
    if (rounds > 0) {
        issue(0, v, ok);
        for (int r = 0; r < rounds; ++r) {
            uint4 vn[2]; int okn[2];
            bool more = (r + 1 < rounds);
            if (more) issue(r + 1, vn, okn);
#pragma unroll
            for (int n = 0; n < 2; ++n) {
                if (ok[n]) {
                    acc[n][0] += bflo(v[n].x); acc[n][1] += bfhi(v[n].x);
                    acc[n][2] += bflo(v[n].y); acc[n][3] += bfhi(v[n].y);
                    acc[n][4] += bflo(v[n].z); acc[n][5] += bfhi(v[n].z);
                    acc[n][6] += bflo(v[n].w); acc[n][7] += bfhi(v[n].w);
                }
            }
            if (more) {
#pragma unroll
                for (int n = 0; n < 2; ++n) { v[n] = vn[n]; ok[n] = okn[n]; }
            }
        }
    }
#pragma unroll
    for (int n = 0; n < 2; ++n) {
#pragma unroll
        for (int d = 0; d < 8; ++d) {
            float t = acc[n][d];
            t += __shfl_xor(t, 8, 64);
            t += __shfl_xor(t, 16, 64);
            t += __shfl_xor(t, 32, 64);
            acc[n][d] = t;
        }
        if (s == 0 && g < 6) {
            float4 p0, p1;
            p0.x = acc[n][0] * sc[n]; p0.y = acc[n][1] * sc[n];
            p0.z = acc[n][2] * sc[n]; p0.w = acc[n][3] * sc[n];
            p1.x = acc[n][4] * sc[n]; p1.y = acc[n][5] * sc[n];
            p1.z = acc[n][6] * sc[n]; p1.w = acc[n][7] * sc[n];
            *(float4*)&aggT[wid * 2 + n][8 * g] = p0;
            *(float4*)&aggT[wid * 2 + n][8 * g + 4] = p1;
        }
    }
    __syncthreads();
    if (wid != 0) return;   // device-fn return: barrier count per call stays uniform

    int nin = lane & 15, kq = lane >> 4;
    f32x4 acc2[3];
#pragma unroll
    for (int j = 0; j < 3; ++j) acc2[j] = (f32x4){0.f, 0.f, 0.f, 0.f};
#pragma unroll
    for (int kt = 0; kt < 4; ++kt) {
        bf16x8 a2 = *(const bf16x8*)(h1 + (size_t)(m0 + nin) * HH + kt * 32 + kq * 8);
#pragma unroll
        for (int j = 0; j < 3; ++j) {
            bf16x8 b2 = *(const bf16x8*)(B2f + (((kt * 3 + j) * 64) + lane) * 8);
            acc2[j] = __builtin_amdgcn_mfma_f32_16x16x32_bf16(a2, b2, acc2[j], 0, 0, 0);
        }
    }
    float bv[3];
#pragma unroll
    for (int t = 0; t < 3; ++t) {
        int col = t * 16 + nin;
        bv[t] = (col < CC) ? bias[col] : 0.f;
    }
#pragma unroll
    for (int r = 0; r < 4; ++r) {
        int m = m0 + kq * 4 + r;
        int ml = kq * 4 + r;
        float v[3];
        float mx = -1e30f;
#pragma unroll
        for (int t = 0; t < 3; ++t) {
            int col = t * 16 + nin;
            v[t] = acc2[t][r] + aggT[ml][col] + bv[t];
            if (col < CC) mx = fmaxf(mx, v[t]);
        }
        for (int off = 1; off < 16; off <<= 1) mx = fmaxf(mx, __shfl_xor(mx, off, 64));
        float sm = 0.f;
#pragma unroll
        for (int t = 0; t < 3; ++t) {
            int col = t * 16 + nin;
            if (col < CC) sm += expf(v[t] - mx);
        }
        for (int off = 1; off < 16; off <<= 1) sm += __shfl_xor(sm, off, 64);
        float lse = mx + logf(sm);
#pragma unroll
        for (int t = 0; t < 3; ++t) {
            int col = t * 16 + nin;
            if (col < CC) out[(size_t)m * CC + col] = v[t] - lse;
        }
    }
}

// ---------------- mega kernel: whole pipeline, one cooperative launch ----------------
struct MegaArgs {
    const int* src;
    const int* dst;
    int* counts;
    int* csr;
    const float* wsrc[8];
    unsigned short* wf[8];
    const float* x;
    unsigned* xb;
    const float* enc_b;
    const float* lay_b;
    const float* dec_b;
    unsigned short* h1;
    unsigned short* h2;
    unsigned short* tbuf;
    float* out;
};

__global__ __launch_bounds__(512, 8) void k_mega(MegaArgs a) {
    cg::grid_group grid = cg::this_grid();
    const int TOT = gridDim.x * 512;
    const int gid = blockIdx.x * 512 + threadIdx.x;

    // ---- A: zero counts + weight swizzle + x->bf16 ----
    for (int i = gid; i < NN; i += TOT) a.counts[i] = 0;
    for (int i = gid; i < 6 * 16384; i += TOT)
        swz_one<HH, HH>(a.wsrc[i >> 14], a.wf[i >> 14], i & 16383);
    for (int i = gid; i < 2 * 6144; i += TOT) {
        int w = 6 + (i >= 6144);
        swz_one<CC, 48>(a.wsrc[w], a.wf[w], i % 6144);
    }
    for (int i = gid; i < NN * HH / 4; i += TOT) {
        float4 v = ((const float4*)a.x)[i];
        uint2 o;
        o.x = ((unsigned)f2bf(v.y) << 16) | f2bf(v.x);
        o.y = ((unsigned)f2bf(v.w) << 16) | f2bf(v.z);
        ((uint2*)a.xb)[i] = o;
    }
    __threadfence();
    grid.sync();

    // ---- B: padded-CSR build (one edge per thread) ----
    for (int e = gid; e < EE; e += TOT) {
        int d = a.dst[e];
        if ((unsigned)d < (unsigned)NN) {
            int sl = atomicAdd(&a.counts[d], 1);
            if (sl < CAP) a.csr[d * CAP + sl] = a.src[e];
        }
    }
    __threadfence();
    grid.sync();

    // ---- C/D/E: layers (tile-strided persistent blocks) ----
    for (int t = blockIdx.x; t < NTILE; t += gridDim.x)
        layer_tile<0>(t, a.h2, a.counts, a.csr, a.wf[0], a.wf[1], a.enc_b, a.h1, nullptr, nullptr);
    __threadfence();
    grid.sync();
    for (int t = blockIdx.x; t < NTILE; t += gridDim.x)
        layer_tile<0>(t, a.h1, a.counts, a.csr, a.wf[2], a.wf[3], a.lay_b, a.h2, nullptr, nullptr);
    __threadfence();
    grid.sync();
    for (int t = blockIdx.x; t < NTILE; t += gridDim.x)
        layer_tile<1>(t, a.h2, a.counts, a.csr, a.wf[4], a.wf[5], a.lay_b + HH, a.h1, a.wf[6], a.tbuf);
    __threadfence();
    grid.sync();

    // ---- F: decoder ----
    for (int t = blockIdx.x; t < NTILE; t += gridDim.x)
        dec_tile(t, a.tbuf, a.h1, a.counts, a.csr, a.wf[7], a.dec_b, a.out);
}

extern "C" void kernel_launch(void* const* d_in, const int* in_sizes, int n_in,
                              void* d_out, int out_size, void* d_ws, size_t ws_size,
                              hipStream_t stream) {
    const float* x      = (const float*)d_in[0];
    const int*   ei     = (const int*)d_in[1];
    const float* enc_Wl = (const float*)d_in[2];
    const float* enc_Wr = (const float*)d_in[3];
    const float* enc_b  = (const float*)d_in[4];
    const float* lay_Wl = (const float*)d_in[5];
    const float* lay_Wr = (const float*)d_in[6];
    const float* lay_b  = (const float*)d_in[7];
    const float* dec_Wl = (const float*)d_in[8];
    const float* dec_Wr = (const float*)d_in[9];
    const float* dec_b  = (const float*)d_in[10];
    float* out = (float*)d_out;

    // ---- workspace carve (256B aligned), total ~39 MB ----
    char* p = (char*)d_ws;
    auto carve = [&](size_t bytes) {
        char* r = p;
        p += (bytes + 255) & ~(size_t)255;
        return r;
    };
    int*            counts = (int*)carve(NN * 4);
    int*            csr    = (int*)carve((size_t)NN * CAP * 4);
    unsigned short* h1     = (unsigned short*)carve((size_t)NN * HH * 2);
    unsigned short* h2     = (unsigned short*)carve((size_t)NN * HH * 2);  // also xb
    unsigned short* tbuf   = (unsigned short*)carve((size_t)NN * 48 * 2 + 256);
    unsigned short* wf[8];
    for (int i = 0; i < 6; ++i) wf[i] = (unsigned short*)carve(HH * HH * 2);
    wf[6] = (unsigned short*)carve(HH * 48 * 2);
    wf[7] = (unsigned short*)carve(HH * 48 * 2);

    MegaArgs a;
    a.src = ei;
    a.dst = ei + EE;
    a.counts = counts;
    a.csr = csr;
    a.wsrc[0] = enc_Wl; a.wsrc[1] = enc_Wr;
    a.wsrc[2] = lay_Wl; a.wsrc[3] = lay_Wr;
    a.wsrc[4] = lay_Wl + HH * HH; a.wsrc[5] = lay_Wr + HH * HH;
    a.wsrc[6] = dec_Wl; a.wsrc[7] = dec_Wr;
    for (int i = 0; i < 8; ++i) a.wf[i] = wf[i];
    a.x = x;
    a.xb = (unsigned*)h2;
    a.enc_b = enc_b;
    a.lay_b = lay_b;
    a.dec_b = dec_b;
    a.h1 = h1;
    a.h2 = h2;
    a.tbuf = tbuf;
    a.out = out;

    // co-resident grid: query occupancy, cap at 1024 blocks (4/CU x 8 waves)
    int maxb = 0;
    hipOccupancyMaxActiveBlocksPerMultiprocessor(&maxb, k_mega, 512, 0);
    if (maxb < 1) maxb = 1;
    int grid = maxb * 256;
    if (grid > 1024) grid = 1024;

    void* kargs[] = {(void*)&a};
    hipLaunchCooperativeKernel((void*)k_mega, dim3(grid), dim3(512), kargs, 0, stream);
}

// Round 14
// 295.705 us; speedup vs baseline: 4.3553x; 4.3553x over previous
//
#include <hip/hip_runtime.h>
#include <hip/hip_bf16.h>

#define NN 50000
#define EE 600000
#define HH 128
#define CC 40
#define NEG 0.1f
#define CAP 40   // padded-CSR capacity; P(deg>40) ~ 1e-10 for Binom(600k, 1/50k)

typedef __attribute__((ext_vector_type(8))) short bf16x8;
typedef __attribute__((ext_vector_type(4))) float f32x4;

__device__ __forceinline__ unsigned short f2bf(float f) {
    unsigned u = __float_as_uint(f);
    unsigned r = u + 0x7fffu + ((u >> 16) & 1u);
    return (unsigned short)(r >> 16);
}
__device__ __forceinline__ float bfhi(unsigned v) { return __uint_as_float(v & 0xFFFF0000u); }
__device__ __forceinline__ float bflo(unsigned v) { return __uint_as_float(v << 16); }

// ---------------- padded-CSR build: one edge per thread (max TLP) ----------------
__global__ void k_build(const int* __restrict__ src, const int* __restrict__ dst,
                        int* __restrict__ counts, int* __restrict__ csr) {
    int e = blockIdx.x * blockDim.x + threadIdx.x;
    if (e < EE) {
        int d = dst[e];
        if ((unsigned)d < (unsigned)NN) {
            int sl = atomicAdd(&counts[d], 1);
            if (sl < CAP) csr[d * CAP + sl] = src[e];
        }
    }
}

// ---------------- k_prep: weight swizzle + counts zero + x->bf16 cast ----------------
struct PrepArgs {
    const float* wsrc[8];
    unsigned short* wdst[8];
    int* counts;
    const float* x;
    unsigned* xb;
};

template <int DOUT, int DOUTP>
__device__ __forceinline__ void swz_one(const float* __restrict__ W,
                                        unsigned short* __restrict__ dstf, int idx) {
    int k = idx / DOUTP, n = idx % DOUTP;
    unsigned short val = (n < DOUT) ? f2bf(W[k * DOUT + n]) : (unsigned short)0;
    int kt = k >> 5, kin = k & 31, nt = n >> 4, nin = n & 15;
    int lane = ((kin >> 3) << 4) | nin;
    int j = kin & 7;
    int NT = DOUTP >> 4;
    dstf[(((kt * NT + nt) * 64) + lane) * 8 + j] = val;
}

// blocks 0..383: six 128x128 weights (+ counts zero); 384..431: two 128x40->48;
// 432..: xcast of x (fp32 -> packed bf16)
__global__ void k_prep(PrepArgs a) {
    int b = blockIdx.x;
    if (b < 384) {
        int tid = b * 256 + threadIdx.x;
        if (tid < NN) a.counts[tid] = 0;
        int which = b >> 6;
        int idx = (b & 63) * 256 + threadIdx.x;
        swz_one<HH, HH>(a.wsrc[which], a.wdst[which], idx);
    } else if (b < 432) {
        int bb = b - 384;
        int which = 6 + bb / 24;
        int idx = (bb % 24) * 256 + threadIdx.x;
        swz_one<CC, 48>(a.wsrc[which], a.wdst[which], idx);
    } else {
        int t = (b - 432) * 256 + threadIdx.x;
        if (t < NN * HH / 4) {
            float4 v = ((const float4*)a.x)[t];
            uint2 o;
            o.x = ((unsigned)f2bf(v.y) << 16) | f2bf(v.x);
            o.y = ((unsigned)f2bf(v.w) << 16) | f2bf(v.z);
            ((uint2*)a.xb)[t] = o;
        }
    }
}

// ---------------- layer kernel: 2-phase gather + double GEMM + lrelu ----------------
// Block = 512 thr = 8 waves = 16 nodes (2 per wave). Gather in 2 dim-phases of
// 64 dims (128B slice). lane = s*8 + g: g = uint4 dim-group, s = edge-slot 0..7.
// MFMA: each wave computes 1 of 8 column tiles (tile = wid).
// MODE 1 (layer 3): stage the lrelu'd 16x128 tile to LDS at stride 132 shorts
// (write banks (8kq+2r+nin/2)%32 -> all 32 banks 2-way, conflict-free
// [verified R12: SQ_LDS_BANK_CONFLICT 200k->0]) and have waves 0..2 compute
// t = tile @ dec_Wl (16x48, 96B rows) fused.
template <int MODE>
__global__ __launch_bounds__(512) void k_layer(
    const unsigned short* __restrict__ hin,    // [N][128] bf16
    const int* __restrict__ counts, const int* __restrict__ csr,
    const unsigned short* __restrict__ B1f, const unsigned short* __restrict__ B2f,
    const float* __restrict__ bias, unsigned short* __restrict__ out,
    const unsigned short* __restrict__ Tf, unsigned short* __restrict__ tOut) {
    __shared__ unsigned lds[16][72];           // MODE1 reuses as [16][132] shorts
    int wid = threadIdx.x >> 6;        // 0..7
    int lane = threadIdx.x & 63;
    int m0 = blockIdx.x * 16;
    int g = lane & 7;
    int s = lane >> 3;
    const uint4* hw4 = (const uint4*)hin;

    int beg[2], cnt[2];
    float sc[2];
    int maxd = 0;
#pragma unroll
    for (int n = 0; n < 2; ++n) {
        int node = m0 + wid * 2 + n;
        int c = counts[node];
        c = c < CAP ? c : CAP;
        beg[n] = node * CAP;
        cnt[n] = c;
        sc[n] = 1.0f / (float)(c > 0 ? c : 1);
        maxd = maxd > c ? maxd : c;
    }
    int rounds = (maxd + 7) >> 3;

    for (int ph = 0; ph < 2; ++ph) {
        float acc[2][8];
#pragma unroll
        for (int n = 0; n < 2; ++n)
#pragma unroll
            for (int d = 0; d < 8; ++d) acc[n][d] = 0.f;

        uint4 v[2]; int ok[2];
        auto issue = [&](int r, uint4* vv, int* okk) {
#pragma unroll
            for (int n = 0; n < 2; ++n) {
                int idx = r * 8 + s;
                int o = idx < cnt[n];
                int row = csr[beg[n] + (o ? idx : 0)];
                vv[n] = hw4[(size_t)row * 16 + ph * 8 + g];
                okk[n] = o;
            }
        };
        if (rounds > 0) {
            issue(0, v, ok);
            for (int r = 0; r < rounds; ++r) {
                uint4 vn[2]; int okn[2];
                bool more = (r + 1 < rounds);
                if (more) issue(r + 1, vn, okn);
#pragma unroll
                for (int n = 0; n < 2; ++n) {
                    if (ok[n]) {
                        acc[n][0] += bflo(v[n].x); acc[n][1] += bfhi(v[n].x);
                        acc[n][2] += bflo(v[n].y); acc[n][3] += bfhi(v[n].y);
                        acc[n][4] += bflo(v[n].z); acc[n][5] += bfhi(v[n].z);
                        acc[n][6] += bflo(v[n].w); acc[n][7] += bfhi(v[n].w);
                    }
                }
                if (more) {
#pragma unroll
                    for (int n = 0; n < 2; ++n) { v[n] = vn[n]; ok[n] = okn[n]; }
                }
            }
        }
        // reduce over slot bits (lane bits 3..5), store 128B LDS slice
#pragma unroll
        for (int n = 0; n < 2; ++n) {
#pragma unroll
            for (int d = 0; d < 8; ++d) {
                float t = acc[n][d];
                t += __shfl_xor(t, 8, 64);
                t += __shfl_xor(t, 16, 64);
                t += __shfl_xor(t, 32, 64);
                acc[n][d] = t;
            }
            if (s == 0) {
                uint4 w4;
                w4.x = ((unsigned)f2bf(acc[n][1] * sc[n]) << 16) | f2bf(acc[n][0] * sc[n]);
                w4.y = ((unsigned)f2bf(acc[n][3] * sc[n]) << 16) | f2bf(acc[n][2] * sc[n]);
                w4.z = ((unsigned)f2bf(acc[n][5] * sc[n]) << 16) | f2bf(acc[n][4] * sc[n]);
                w4.w = ((unsigned)f2bf(acc[n][7] * sc[n]) << 16) | f2bf(acc[n][6] * sc[n]);
                *(uint4*)&lds[wid * 2 + n][ph * 32 + g * 4] = w4;
            }
        }
    }
    __syncthreads();

    // ---- MFMA: A1 from LDS, A2 = self row; 1 col-tile per wave (tile = wid) ----
    int nin = lane & 15;
    int kq = lane >> 4;
    const unsigned* arow = &lds[nin][0];

    f32x4 acc1 = (f32x4){0.f, 0.f, 0.f, 0.f};

#pragma unroll
    for (int kt = 0; kt < 4; ++kt) {
        bf16x8 a1 = *(const bf16x8*)(arow + kt * 16 + kq * 4);
        bf16x8 a2 = *(const bf16x8*)(hin + (size_t)(m0 + nin) * HH + kt * 32 + kq * 8);
        bf16x8 b1 = *(const bf16x8*)(B1f + (((kt * 8 + wid) * 64) + lane) * 8);
        acc1 = __builtin_amdgcn_mfma_f32_16x16x32_bf16(a1, b1, acc1, 0, 0, 0);
        bf16x8 b2 = *(const bf16x8*)(B2f + (((kt * 8 + wid) * 64) + lane) * 8);
        acc1 = __builtin_amdgcn_mfma_f32_16x16x32_bf16(a2, b2, acc1, 0, 0, 0);
    }

    // C/D: col = lane&15, row = (lane>>4)*4 + reg
    int col = wid * 16 + nin;
    float bv = bias[col];
    unsigned short hv[4];
#pragma unroll
    for (int r = 0; r < 4; ++r) {
        int m = m0 + kq * 4 + r;
        float v = acc1[r] + bv;
        v = fmaxf(v, NEG * v);
        hv[r] = f2bf(v);
        out[(size_t)m * HH + col] = hv[r];
    }

    if (MODE == 1) {
        // stage lrelu'd tile to LDS (stride 132 shorts, conflict-free), then
        // waves 0..2 compute t = tile @ dec_Wl (3 col tiles of 16).
        __syncthreads();
        unsigned short* lsh = (unsigned short*)&lds[0][0];   // [16][132] shorts
#pragma unroll
        for (int r = 0; r < 4; ++r) lsh[(kq * 4 + r) * 132 + col] = hv[r];
        __syncthreads();
        if (wid < 3) {
            f32x4 at = (f32x4){0.f, 0.f, 0.f, 0.f};
#pragma unroll
            for (int kt = 0; kt < 4; ++kt) {
                bf16x8 a = *(const bf16x8*)&lsh[nin * 132 + kt * 32 + kq * 8];
                bf16x8 b = *(const bf16x8*)(Tf + (((kt * 3 + wid) * 64) + lane) * 8);
                at = __builtin_amdgcn_mfma_f32_16x16x32_bf16(a, b, at, 0, 0, 0);
            }
#pragma unroll
            for (int r = 0; r < 4; ++r) {
                int m = m0 + kq * 4 + r;
                tOut[(size_t)m * 48 + wid * 16 + nin] = f2bf(at[r]);
            }
        }
    }
}

// ---------------- k_dec: gather t (96B rows) + h1@Wr + bias + log_softmax ----------------
__global__ __launch_bounds__(512) void k_dec(
    const unsigned short* __restrict__ tbuf,   // [N][48] bf16, 96B rows
    const unsigned short* __restrict__ h1,
    const int* __restrict__ counts, const int* __restrict__ csr,
    const unsigned short* __restrict__ B2f, const float* __restrict__ bias,
    float* __restrict__ out) {
    __shared__ float aggT[16][52];
    int wid = threadIdx.x >> 6;        // 0..7
    int lane = threadIdx.x & 63;
    int m0 = blockIdx.x * 16;
    int g = lane & 7;
    int g6 = g < 6 ? g : g - 6;        // lanes 6,7 duplicate slices 0,1 (same cache lines)
    int s = lane >> 3;                 // 8 edge-slots
    const uint4* t4 = (const uint4*)tbuf;

    int beg[2], cnt[2];
    float sc[2];
    int maxd = 0;
#pragma unroll
    for (int n = 0; n < 2; ++n) {
        int node = m0 + wid * 2 + n;
        int c = counts[node];
        c = c < CAP ? c : CAP;
        beg[n] = node * CAP;
        cnt[n] = c;
        sc[n] = 1.0f / (float)(c > 0 ? c : 1);
        maxd = maxd > c ? maxd : c;
    }
    int rounds = (maxd + 7) >> 3;

    float acc[2][8];
#pragma unroll
    for (int n = 0; n < 2; ++n)
#pragma unroll
        for (int d = 0; d < 8; ++d) acc[n][d] = 0.f;

    uint4 v[2]; int ok[2];
    auto issue = [&](int r, uint4* vv, int* okk) {
#pragma unroll
        for (int n = 0; n < 2; ++n) {
            int idx = r * 8 + s;
            int o = idx < cnt[n];
            int row = csr[beg[n] + (o ? idx : 0)];
            vv[n] = t4[(size_t)row * 6 + g6];
            okk[n] = o;
        }
    };
    if (rounds > 0) {
        issue(0, v, ok);
        for (int r = 0; r < rounds; ++r) {
            uint4 vn[2]; int okn[2];
            bool more = (r + 1 < rounds);
            if (more) issue(r + 1, vn, okn);
#pragma unroll
            for (int n = 0; n < 2; ++n) {
                if (ok[n]) {
                    acc[n][0] += bflo(v[n].x); acc[n][1] += bfhi(v[n].x);
                    acc[n][2] += bflo(v[n].y); acc[n][3] += bfhi(v[n].y);
                    acc[n][4] += bflo(v[n].z); acc[n][5] += bfhi(v[n].z);
                    acc[n][6] += bflo(v[n].w); acc[n][7] += bfhi(v[n].w);
                }
            }
            if (more) {
#pragma unroll
                for (int n = 0; n < 2; ++n) { v[n] = vn[n]; ok[n] = okn[n]; }
            }
        }
    }
#pragma unroll
    for (int n = 0; n < 2; ++n) {
#pragma unroll
        for (int d = 0; d < 8; ++d) {
            float t = acc[n][d];
            t += __shfl_xor(t, 8, 64);
            t += __shfl_xor(t, 16, 64);
            t += __shfl_xor(t, 32, 64);
            acc[n][d] = t;
        }
        if (s == 0 && g < 6) {
            float4 p0, p1;
            p0.x = acc[n][0] * sc[n]; p0.y = acc[n][1] * sc[n];
            p0.z = acc[n][2] * sc[n]; p0.w = acc[n][3] * sc[n];
            p1.x = acc[n][4] * sc[n]; p1.y = acc[n][5] * sc[n];
            p1.z = acc[n][6] * sc[n]; p1.w = acc[n][7] * sc[n];
            *(float4*)&aggT[wid * 2 + n][8 * g] = p0;
            *(float4*)&aggT[wid * 2 + n][8 * g + 4] = p1;
        }
    }
    __syncthreads();
    if (wid != 0) return;

    int nin = lane & 15, kq = lane >> 4;
    f32x4 acc2[3];
#pragma unroll
    for (int j = 0; j < 3; ++j) acc2[j] = (f32x4){0.f, 0.f, 0.f, 0.f};
#pragma unroll
    for (int kt = 0; kt < 4; ++kt) {
        bf16x8 a2 = *(const bf16x8*)(h1 + (size_t)(m0 + nin) * HH + kt * 32 + kq * 8);
#pragma unroll
        for (int j = 0; j < 3; ++j) {
            bf16x8 b2 = *(const bf16x8*)(B2f + (((kt * 3 + j) * 64) + lane) * 8);
            acc2[j] = __builtin_amdgcn_mfma_f32_16x16x32_bf16(a2, b2, acc2[j], 0, 0, 0);
        }
    }
    float bv[3];
#pragma unroll
    for (int t = 0; t < 3; ++t) {
        int col = t * 16 + nin;
        bv[t] = (col < CC) ? bias[col] : 0.f;
    }
#pragma unroll
    for (int r = 0; r < 4; ++r) {
        int m = m0 + kq * 4 + r;
        int ml = kq * 4 + r;
        float v[3];
        float mx = -1e30f;
#pragma unroll
        for (int t = 0; t < 3; ++t) {
            int col = t * 16 + nin;
            v[t] = acc2[t][r] + aggT[ml][col] + bv[t];
            if (col < CC) mx = fmaxf(mx, v[t]);
        }
        for (int off = 1; off < 16; off <<= 1) mx = fmaxf(mx, __shfl_xor(mx, off, 64));
        float sm = 0.f;
#pragma unroll
        for (int t = 0; t < 3; ++t) {
            int col = t * 16 + nin;
            if (col < CC) sm += expf(v[t] - mx);
        }
        for (int off = 1; off < 16; off <<= 1) sm += __shfl_xor(sm, off, 64);
        float lse = mx + logf(sm);
#pragma unroll
        for (int t = 0; t < 3; ++t) {
            int col = t * 16 + nin;
            if (col < CC) out[(size_t)m * CC + col] = v[t] - lse;
        }
    }
}

extern "C" void kernel_launch(void* const* d_in, const int* in_sizes, int n_in,
                              void* d_out, int out_size, void* d_ws, size_t ws_size,
                              hipStream_t stream) {
    const float* x      = (const float*)d_in[0];
    const int*   ei     = (const int*)d_in[1];
    const float* enc_Wl = (const float*)d_in[2];
    const float* enc_Wr = (const float*)d_in[3];
    const float* enc_b  = (const float*)d_in[4];
    const float* lay_Wl = (const float*)d_in[5];
    const float* lay_Wr = (const float*)d_in[6];
    const float* lay_b  = (const float*)d_in[7];
    const float* dec_Wl = (const float*)d_in[8];
    const float* dec_Wr = (const float*)d_in[9];
    const float* dec_b  = (const float*)d_in[10];
    float* out = (float*)d_out;

    const int* src = ei;
    const int* dst = ei + EE;

    // ---- workspace carve (256B aligned), total ~39 MB ----
    char* p = (char*)d_ws;
    auto carve = [&](size_t bytes) {
        char* r = p;
        p += (bytes + 255) & ~(size_t)255;
        return r;
    };
    int*            counts = (int*)carve(NN * 4);
    int*            csr    = (int*)carve((size_t)NN * CAP * 4);
    unsigned short* h1     = (unsigned short*)carve((size_t)NN * HH * 2);
    unsigned short* h2     = (unsigned short*)carve((size_t)NN * HH * 2);  // also xb
    unsigned short* tbuf   = (unsigned short*)carve((size_t)NN * 48 * 2 + 256);  // +pad for g-dupe reads
    unsigned short* wf[8];
    for (int i = 0; i < 6; ++i) wf[i] = (unsigned short*)carve(HH * HH * 2);
    wf[6] = (unsigned short*)carve(HH * 48 * 2);
    wf[7] = (unsigned short*)carve(HH * 48 * 2);

    // prep: weight swizzles + counts zero + x->bf16 (one launch)
    {
        PrepArgs a;
        a.wsrc[0] = enc_Wl; a.wsrc[1] = enc_Wr;
        a.wsrc[2] = lay_Wl; a.wsrc[3] = lay_Wr;
        a.wsrc[4] = lay_Wl + HH * HH; a.wsrc[5] = lay_Wr + HH * HH;
        a.wsrc[6] = dec_Wl; a.wsrc[7] = dec_Wr;
        for (int i = 0; i < 8; ++i) a.wdst[i] = wf[i];
        a.counts = counts;
        a.x = x;
        a.xb = (unsigned*)h2;
        k_prep<<<432 + (NN * HH / 4 + 255) / 256, 256, 0, stream>>>(a);
    }

    // padded-CSR build: one edge per thread
    k_build<<<(EE + 255) / 256, 256, 0, stream>>>(src, dst, counts, csr);

    // layers: 3125 blocks x 8 waves (2 nodes/wave); layer 3 fuses t = h1 @ dec_Wl
    const int FB = NN / 16;   // 3125
    k_layer<0><<<FB, 512, 0, stream>>>(h2, counts, csr, wf[0], wf[1], enc_b,      h1, nullptr, nullptr);
    k_layer<0><<<FB, 512, 0, stream>>>(h1, counts, csr, wf[2], wf[3], lay_b,      h2, nullptr, nullptr);
    k_layer<1><<<FB, 512, 0, stream>>>(h2, counts, csr, wf[4], wf[5], lay_b + HH, h1, wf[6], tbuf);

    // decoder: gather t + h1@Wr + log_softmax
    k_dec<<<FB, 512, 0, stream>>>(tbuf, h1, counts, csr, wf[7], dec_b, out);
}